// Round 15
// baseline (856.523 us; speedup 1.0000x reference)
//
#include <hip/hip_runtime.h>

// ---------------------------------------------------------------------------
// SequenceModel: embed -> 2x transformer layer (flash attention) -> 3 projections
// All activations and the residual stream are f16 (accum f32 inside kernels).
// GEMMs: C[M,N] = alpha * A[M,K] @ B[N,K]^T (+bias[col]) (+f16 resid) (relu)
// gemm_nt<MODE>: MODE=0: BK=32, 2-buf, 32KB LDS (grid-rich shapes, 5/CU).
//                MODE=1: BK=64, 2-buf, 64KB LDS (grid-starved N=512 shapes:
//                  Wo, W2 -- their 512-block grids cap at 2 blocks/CU anyway;
//                  fatter K-steps halve barrier/waitcnt overhead per MFMA).
// QKV GEMM epilogue scatters V directly into vT[bh][d][s] (vtrans deleted).
// flash_k: 8-wave QBLK=128, bias as MFMA C-init, in-register P exchange,
//   dbuf K/V via gload_lds.
// ---------------------------------------------------------------------------

typedef _Float16 half8 __attribute__((ext_vector_type(8)));
typedef _Float16 half4 __attribute__((ext_vector_type(4)));
typedef float f32x4 __attribute__((ext_vector_type(4)));
typedef unsigned int uint2v __attribute__((ext_vector_type(2)));
typedef unsigned int uint4v __attribute__((ext_vector_type(4)));

__device__ __forceinline__ void gl2lds16(const _Float16* g, _Float16* l) {
    __builtin_amdgcn_global_load_lds(
        (const __attribute__((address_space(1))) void*)g,
        (__attribute__((address_space(3))) void*)l, 16, 0, 0);
}

// ------------------- cast f32->f16 with zero-pad tail ----------------------
__global__ void cast_f32_f16_k(const float* __restrict__ in, _Float16* __restrict__ out,
                               long nsrc, long ntot) {
    long i = (long)blockIdx.x * blockDim.x + threadIdx.x;
    long stride = (long)gridDim.x * blockDim.x;
    for (; i < ntot; i += stride) out[i] = i < nsrc ? (_Float16)in[i] : (_Float16)0.f;
}

// ------ transpose+cast: in (Z,R,C) f32 -> out + z*zs + (rowoff+c)*R f16 ----
__global__ void tcast_k(const float* __restrict__ in, _Float16* __restrict__ out,
                        int R, int C, long zs, int rowoff) {
    __shared__ float tile[32][33];
    long z = blockIdx.z;
    const float* src = in + z * (long)R * C;
    _Float16* dst = out + z * zs + (long)rowoff * R;
    int c0 = blockIdx.x * 32, r0 = blockIdx.y * 32;
    for (int i = threadIdx.y; i < 32; i += 8)
        tile[i][threadIdx.x] = src[(long)(r0 + i) * C + c0 + threadIdx.x];
    __syncthreads();
    for (int i = threadIdx.y; i < 32; i += 8)
        dst[(long)(c0 + i) * R + r0 + threadIdx.x] = (_Float16)tile[threadIdx.x][i];
}

// --------------------------- bias concat q|k|v ------------------------------
__global__ void bcat_k(const float* __restrict__ bq, const float* __restrict__ bk,
                       const float* __restrict__ bv, float* __restrict__ out, int L) {
    int i = blockIdx.x * 256 + threadIdx.x;
    if (i >= L * 1536) return;
    int l = i / 1536, j = i - l * 1536;
    float v = j < 512 ? bq[l * 512 + j] : (j < 1024 ? bk[l * 512 + j - 512] : bv[l * 512 + j - 1024]);
    out[i] = v;
}

// ------------------------------- embedding ---------------------------------
__global__ __launch_bounds__(128) void embed_k(
    const int* __restrict__ ccat, const float* __restrict__ ctime, const float* __restrict__ cf0,
    const int* __restrict__ tcat, const float* __restrict__ ttime, const float* __restrict__ tf0,
    const float* __restrict__ cat_table, const float* __restrict__ pad_emb,
    _Float16* __restrict__ xb, float* __restrict__ biasKey) {
    int t = blockIdx.x;             // token 0..16383
    int b = t >> 10, s = t & 1023;
    int j = b * 512 + (s & 511);
    int cat; float tm, f0;
    if (s < 512) { cat = ccat[j]; tm = ctime[j]; f0 = cf0[j]; }
    else         { cat = tcat[j]; tm = ttime[j]; f0 = tf0[j]; }
    bool pad = cat < 0;
    if (threadIdx.x == 0) biasKey[t] = pad ? -1e9f : 0.f;
    int c = cat < 0 ? 0 : cat;
    half4 h4;
    #pragma unroll
    for (int u = 0; u < 4; u++) {
        int d = threadIdx.x * 4 + u;   // 0..511
        float val;
        if (pad) val = pad_emb[d];
        else if (d < 256) val = cat_table[(long)c * 256 + d];
        else {
            float base = (d < 384) ? tm : f0;
            int i = (d < 384) ? (d - 256) : (d - 384);
            float ang = base / powf(1000.f, (float)i * (1.f / 128.f));
            val = (i & 1) ? cosf(ang) : sinf(ang);
        }
        h4[u] = (_Float16)val;
    }
    *(half4*)&xb[(long)t * 512 + threadIdx.x * 4] = h4;
}

// ------------------------------ layernorm (f16 in/out) ---------------------
__global__ __launch_bounds__(256) void layernorm_k(
    const _Float16* __restrict__ in, _Float16* __restrict__ out,
    const float* __restrict__ g, const float* __restrict__ beta) {
    long row = blockIdx.x;
    int tid = threadIdx.x;
    const unsigned* rw = (const unsigned*)(in + row * 512);
    unsigned wo = rw[tid];
    float v0 = (float)(_Float16)__builtin_bit_cast(_Float16, (unsigned short)(wo & 0xffff));
    float v1 = (float)(_Float16)__builtin_bit_cast(_Float16, (unsigned short)(wo >> 16));
    float s = v0 + v1, q = v0 * v0 + v1 * v1;
    #pragma unroll
    for (int o = 32; o; o >>= 1) { s += __shfl_down(s, o); q += __shfl_down(q, o); }
    __shared__ float rs[4], rq[4];
    if ((tid & 63) == 0) { rs[tid >> 6] = s; rq[tid >> 6] = q; }
    __syncthreads();
    s = rs[0] + rs[1] + rs[2] + rs[3];
    q = rq[0] + rq[1] + rq[2] + rq[3];
    float mean = s * (1.f / 512.f);
    float var = q * (1.f / 512.f) - mean * mean;
    float rstd = rsqrtf(var + 1e-5f);
    float y0 = (v0 - mean) * rstd * g[tid * 2] + beta[tid * 2];
    float y1 = (v1 - mean) * rstd * g[tid * 2 + 1] + beta[tid * 2 + 1];
    unsigned short u0 = __builtin_bit_cast(unsigned short, (_Float16)y0);
    unsigned short u1 = __builtin_bit_cast(unsigned short, (_Float16)y1);
    ((unsigned*)(out + row * 512))[tid] = (unsigned)u0 | ((unsigned)u1 << 16);
}

// ------------------------------ flash attention ----------------------------
// grid (B*H, S/128), 512 threads = 8 waves, wave w handles 16 q rows.
// KVBLK=64 dbuf via global_load_lds (XOR-slot source swizzle). Key-pad bias
// enters as the QK MFMA C-initializer. P->A-operand exchange in-register:
// cvt_pkrtz packs, permlane32_swap, ds_swizzle. exp2-domain softmax,
// defer-max THR=8 (log2), setprio around MFMA.
__global__ __launch_bounds__(512, 4) void flash_k(
    const _Float16* __restrict__ QKV, const _Float16* __restrict__ VT,
    const float* __restrict__ biasKey, _Float16* __restrict__ O) {
    const int S = 1024, D = 512, LDQ = 1536, NT = 16;
    int bh = blockIdx.x; int b = bh >> 3, h = bh & 7;
    int qt = blockIdx.y;
    int tid = threadIdx.x, w = tid >> 6, lane = tid & 63;
    int g = lane >> 4, q15 = lane & 15;

    __shared__ __align__(16) _Float16 Ks[2][64 * 64];   // [kv][d], 8x16B slots/row
    __shared__ __align__(16) _Float16 VTs[2][64 * 64];  // [d][kv]
    __shared__ __align__(16) float biasLds[1024];

    {   // bias * log2(e) (0 or -1.44e9)
        const float* bsrc = biasKey + (long)b * S;
        biasLds[tid]       = bsrc[tid] * 1.442695041f;
        biasLds[tid + 512] = bsrc[tid + 512] * 1.442695041f;
    }

    // Q fragments, pre-scaled by 0.125*log2(e)
    int qrow = qt * 128 + w * 16 + q15;
    const _Float16* qp = QKV + ((long)(b * S + qrow)) * LDQ + h * 64 + g * 8;
    half8 qf[2];
    qf[0] = *(const half8*)(qp);
    qf[1] = *(const half8*)(qp + 32);
    const _Float16 qsc = (_Float16)0.1803368801f;
    #pragma unroll
    for (int kk = 0; kk < 2; kk++)
        #pragma unroll
        for (int i = 0; i < 8; i++) qf[kk][i] *= qsc;

    const _Float16* kbase = QKV + 512 + ((long)b * S) * LDQ + h * 64;
    const _Float16* vbase = VT + (long)bh * 64 * S;

    auto stageK = [&](int buf, int kt) {
        int row = tid >> 3, p = tid & 7;
        int s = p ^ (row & 7);
        gl2lds16(kbase + (long)(kt * 64 + row) * LDQ + s * 8, &Ks[buf][tid * 8]);
    };
    auto stageV = [&](int buf, int kt) {
        int row = tid >> 3, p = tid & 7;
        int s = p ^ (row & 7);
        gl2lds16(vbase + (long)row * S + kt * 64 + s * 8, &VTs[buf][tid * 8]);
    };

    f32x4 acc_o[4];
    #pragma unroll
    for (int i = 0; i < 4; i++)
        #pragma unroll
        for (int r = 0; r < 4; r++) acc_o[i][r] = 0.f;
    float m_run = -1e30f, l_run = 0.f;
    bool gOdd = (g & 1) != 0;

    // QK^T swapped: lane owns q=q15, keys 16*mf+4*g+r; bias enters as C-init.
    auto QK = [&](int kt, f32x4 (&s)[4]) {
        #pragma unroll
        for (int mf = 0; mf < 4; mf++)
            s[mf] = *(const f32x4*)&biasLds[kt * 64 + mf * 16 + g * 4];
        int buf = kt & 1;
        __builtin_amdgcn_s_setprio(1);
        #pragma unroll
        for (int kk = 0; kk < 2; kk++)
            #pragma unroll
            for (int mf = 0; mf < 4; mf++) {
                int row = mf * 16 + q15;
                half8 kf = *(const half8*)&Ks[buf][row * 64 + (((kk * 4 + g) ^ (row & 7)) * 8)];
                s[mf] = __builtin_amdgcn_mfma_f32_16x16x32_f16(kf, qf[kk], s[mf], 0, 0, 0);
            }
        __builtin_amdgcn_s_setprio(0);
    };

    auto SMPV = [&](int kt, f32x4 (&s)[4]) {
        float t0 = fmaxf(fmaxf(s[0][0], s[0][1]), fmaxf(s[0][2], s[0][3]));
        float t1 = fmaxf(fmaxf(s[1][0], s[1][1]), fmaxf(s[1][2], s[1][3]));
        float t2 = fmaxf(fmaxf(s[2][0], s[2][1]), fmaxf(s[2][2], s[2][3]));
        float t3 = fmaxf(fmaxf(s[3][0], s[3][1]), fmaxf(s[3][2], s[3][3]));
        float mt = fmaxf(fmaxf(t0, t1), fmaxf(t2, t3));
        mt = fmaxf(mt, __shfl_xor(mt, 16));
        mt = fmaxf(mt, __shfl_xor(mt, 32));

        float rsum = 0.f;
        if (__all(mt - m_run <= 8.f)) {
            #pragma unroll
            for (int mf = 0; mf < 4; mf++)
                #pragma unroll
                for (int r = 0; r < 4; r++) {
                    float p = exp2f(s[mf][r] - m_run);
                    s[mf][r] = p; rsum += p;
                }
        } else {
            float m_new = fmaxf(m_run, mt);
            float scale = exp2f(m_run - m_new);
            #pragma unroll
            for (int mf = 0; mf < 4; mf++)
                #pragma unroll
                for (int r = 0; r < 4; r++) {
                    float p = exp2f(s[mf][r] - m_new);
                    s[mf][r] = p; rsum += p;
                }
            float sc[4];
            #pragma unroll
            for (int r = 0; r < 4; r++) sc[r] = __shfl(scale, g * 4 + r);
            #pragma unroll
            for (int nf = 0; nf < 4; nf++)
                #pragma unroll
                for (int r = 0; r < 4; r++) acc_o[nf][r] *= sc[r];
            l_run *= scale;
            m_run = m_new;
        }
        rsum += __shfl_xor(rsum, 16);
        rsum += __shfl_xor(rsum, 32);
        l_run += rsum;

        unsigned pk[4][2];
        #pragma unroll
        for (int mf = 0; mf < 4; mf++) {
            auto h0 = __builtin_amdgcn_cvt_pkrtz(s[mf][0], s[mf][1]);
            auto h1 = __builtin_amdgcn_cvt_pkrtz(s[mf][2], s[mf][3]);
            pk[mf][0] = __builtin_bit_cast(unsigned, h0);
            pk[mf][1] = __builtin_bit_cast(unsigned, h1);
        }

        int buf = kt & 1;
        #pragma unroll
        for (int kk = 0; kk < 2; kk++) {
            unsigned wA[2], wB[2];
            #pragma unroll
            for (int wi = 0; wi < 2; wi++) {
                uint2v r2 = __builtin_amdgcn_permlane32_swap(
                    pk[2 * kk][wi], pk[2 * kk + 1][wi], false, false);
                unsigned na = r2[0];
                unsigned nb = r2[1];
                unsigned sa = (unsigned)__builtin_amdgcn_ds_swizzle((int)na, 0x401F); // lane^16
                unsigned sb = (unsigned)__builtin_amdgcn_ds_swizzle((int)nb, 0x401F);
                wA[wi] = gOdd ? sb : na;
                wB[wi] = gOdd ? nb : sa;
            }
            uint4v paw;
            paw[0] = wA[0]; paw[1] = wA[1]; paw[2] = wB[0]; paw[3] = wB[1];
            half8 pa = __builtin_bit_cast(half8, paw);
            __builtin_amdgcn_s_setprio(1);
            #pragma unroll
            for (int nf = 0; nf < 4; nf++) {
                int row = nf * 16 + q15;
                half8 vf = *(const half8*)&VTs[buf][row * 64 + (((kk * 4 + g) ^ (row & 7)) * 8)];
                acc_o[nf] = __builtin_amdgcn_mfma_f32_16x16x32_f16(pa, vf, acc_o[nf], 0, 0, 0);
            }
            __builtin_amdgcn_s_setprio(0);
        }
    };

    f32x4 sA[4], sB[4];
    stageK(0, 0); stageV(0, 0); stageK(1, 1);
    __syncthreads();          // prologue stages landed (also covers biasLds)
    QK(0, sA);

    for (int t = 0; t < NT; t += 2) {
        __syncthreads();
        if (t + 2 < NT) stageK(t & 1, t + 2);
        if (t + 1 < NT) stageV((t + 1) & 1, t + 1);
        if (t + 1 < NT) QK(t + 1, sB);          // MFMA in flight over softmax(t)
        SMPV(t, sA);
        __syncthreads();
        if (t + 3 < NT) stageK((t + 1) & 1, t + 3);
        if (t + 2 < NT) stageV(t & 1, t + 2);
        if (t + 2 < NT) QK(t + 2, sA);
        SMPV(t + 1, sB);
    }

    float linv = 1.f / l_run;
    float lv[4];
    #pragma unroll
    for (int r = 0; r < 4; r++) lv[r] = __shfl(linv, g * 4 + r);
    _Float16* obase = O + ((long)(b * S + qt * 128 + w * 16)) * D + h * 64;
    #pragma unroll
    for (int nf = 0; nf < 4; nf++)
        #pragma unroll
        for (int r = 0; r < 4; r++) {
            int row = g * 4 + r;
            obase[(long)row * D + nf * 16 + q15] = (_Float16)(acc_o[nf][r] * lv[r]);
        }
}

// ------------------------------ batched NT GEMM ----------------------------
// 128x128 tile, 2-buf LDS, global_load_lds 16B, slot-swizzled, XCD-chunked.
// MODE=0: BK=32 (32KB LDS, 5 blocks/CU) for grid-rich shapes.
// MODE=1: BK=64 (64KB LDS, 2 blocks/CU) for grid-starved shapes: halves the
//         barrier/waitcnt count per unit K (32 MFMA per step).
// vt: if non-null, cols >= 1024 are V-columns scattered to vt[bh][d][s].
// Requires M%128==0, K%BK==0, B rows >= ceil128(N) (pad B if needed).
template<int MODE>
__global__ __launch_bounds__(256) void gemm_nt(
    const _Float16* __restrict__ A, long lda, long sA1, long sA2,
    const _Float16* __restrict__ Bm, long ldb, long sB1, long sB2,
    float* Cf, _Float16* Cb, long ldc, long sC1, long sC2,
    const float* __restrict__ bias, long sb1, long sb2,
    const _Float16* resid, _Float16* vt,
    int M, int N, int K, int Z2, float alpha, int relu) {
    constexpr int BK = MODE ? 64 : 32;
    constexpr int SLOTS = BK / 8;           // 16B slots per row
    constexpr int LPS = (128 * BK / 8) / 256;  // loads per thread per matrix

    int z = blockIdx.z;
    int z1 = z / Z2, z2 = z - z1 * Z2;
    A  += z1 * sA1 + z2 * sA2;
    Bm += z1 * sB1 + z2 * sB2;
    long coff = z1 * sC1 + z2 * sC2;
    if (bias) bias += z1 * sb1 + z2 * sb2;

    // XCD-chunked bijective block swizzle over (y,x)
    int gx = gridDim.x;
    int nwg = gx * gridDim.y;
    int bid = blockIdx.y * gx + blockIdx.x;
    int q = nwg >> 3, r = nwg & 7;
    int xcd = bid & 7, ii = bid >> 3;
    int swz = (xcd < r ? xcd * (q + 1) : r * (q + 1) + (xcd - r) * q) + ii;
    int m0 = (swz / gx) * 128;
    int n0 = (swz % gx) * 128;

    __shared__ __align__(16) _Float16 As[2][128 * BK];
    __shared__ __align__(16) _Float16 Bs[2][128 * BK];

    int tid = threadIdx.x;
    int lane = tid & 63;
    int w = tid >> 6;
    int wr = (w >> 1) << 6;
    int wc = (w & 1) << 6;

    f32x4 acc[4][4];
    #pragma unroll
    for (int i = 0; i < 4; i++)
        #pragma unroll
        for (int jj = 0; jj < 4; jj++) { acc[i][jj][0] = 0.f; acc[i][jj][1] = 0.f; acc[i][jj][2] = 0.f; acc[i][jj][3] = 0.f; }

    int fr = lane & 15;
    int g = lane >> 4;

    auto stage = [&](int buf, int kt) {
        #pragma unroll
        for (int i = 0; i < LPS; i++) {
            int idx = tid + i * 256;
            int row = idx / SLOTS, s = idx % SLOTS;
            int sg = s ^ (row & (SLOTS - 1));
            gl2lds16(A + (long)(m0 + row) * lda + kt * BK + sg * 8, &As[buf][idx * 8]);
            gl2lds16(Bm + (long)(n0 + row) * ldb + kt * BK + sg * 8, &Bs[buf][idx * 8]);
        }
    };

    auto compute = [&](int cur) {
        #pragma unroll
        for (int kk = 0; kk < BK / 32; kk++) {
            half8 af[4], bfv[4];
            #pragma unroll
            for (int m = 0; m < 4; m++) {
                int row = wr + m * 16 + fr;
                af[m] = *(const half8*)&As[cur][row * BK + (((kk * 4 + g) ^ (row & (SLOTS - 1))) * 8)];
            }
            #pragma unroll
            for (int n = 0; n < 4; n++) {
                int row = wc + n * 16 + fr;
                bfv[n] = *(const half8*)&Bs[cur][row * BK + (((kk * 4 + g) ^ (row & (SLOTS - 1))) * 8)];
            }
            #pragma unroll
            for (int m = 0; m < 4; m++)
                #pragma unroll
                for (int n = 0; n < 4; n++)
                    acc[m][n] = __builtin_amdgcn_mfma_f32_16x16x32_f16(af[m], bfv[n], acc[m][n], 0, 0, 0);
        }
    };

    int nk = K / BK;
    stage(0, 0);
    for (int t = 0; t < nk; ++t) {
        __builtin_amdgcn_s_barrier();            // readers of buf[(t+1)&1] done
        if (t + 1 < nk) {
            stage((t + 1) & 1, t + 1);           // issue next stage early
            if constexpr (MODE == 0)
                asm volatile("s_waitcnt vmcnt(4)" ::: "memory");   // stage(t) landed
            else
                asm volatile("s_waitcnt vmcnt(8)" ::: "memory");
        } else {
            asm volatile("s_waitcnt vmcnt(0)" ::: "memory");
        }
        __builtin_amdgcn_s_barrier();            // all waves' stage(t) landed
        __builtin_amdgcn_sched_barrier(0);
        compute(t & 1);
    }

    int fq = lane >> 4;
    #pragma unroll
    for (int m = 0; m < 4; m++) {
        #pragma unroll
        for (int jj = 0; jj < 4; jj++) {
            long row = m0 + wr + m * 16 + fq * 4 + jj;
            #pragma unroll
            for (int n = 0; n < 4; n++) {
                int col = n0 + wc + n * 16 + fr;
                if (col < N) {
                    float v = acc[m][n][jj] * alpha;
                    if (bias) v += bias[col];
                    if (vt && col >= 1024) {
                        // V-column: scatter transposed to vt[b*8+h][d][s]
                        int dv = col - 1024;
                        long bh = (row >> 10) * 8 + (dv >> 6);
                        vt[bh * 65536 + (long)(dv & 63) * 1024 + (row & 1023)] = (_Float16)v;
                    } else {
                        long o = coff + row * ldc + col;
                        if (resid) v += (float)resid[o];
                        if (relu) v = fmaxf(v, 0.f);
                        if (Cf) Cf[o] = v;
                        if (Cb) Cb[o] = (_Float16)v;
                    }
                }
            }
        }
    }
}

// ---------------------------------------------------------------------------
extern "C" void kernel_launch(void* const* d_in, const int* in_sizes, int n_in,
                              void* d_out, int out_size, void* d_ws, size_t ws_size,
                              hipStream_t stream) {
    const int Bn = 16, S = 1024, D = 512, H = 8, L = 2, DFF = 2048, NCAT = 1000, NCONT = 2048;
    const long M = (long)Bn * S;

    const int*   ccat      = (const int*)d_in[0];
    const float* ctime     = (const float*)d_in[1];
    const float* cf0       = (const float*)d_in[2];
    const int*   tcat      = (const int*)d_in[3];
    const float* ttime     = (const float*)d_in[4];
    const float* tf0       = (const float*)d_in[5];
    const float* cat_table = (const float*)d_in[6];
    const float* cont_tab  = (const float*)d_in[7];
    const float* pad_emb   = (const float*)d_in[8];
    const float* Wq = (const float*)d_in[9];
    const float* bq = (const float*)d_in[10];
    const float* Wk = (const float*)d_in[11];
    const float* bk = (const float*)d_in[12];
    const float* Wv = (const float*)d_in[13];
    const float* bv = (const float*)d_in[14];
    const float* Wo = (const float*)d_in[15];
    const float* bo = (const float*)d_in[16];
    const float* ln1g = (const float*)d_in[17];
    const float* ln1b = (const float*)d_in[18];
    const float* ln2g = (const float*)d_in[19];
    const float* ln2b = (const float*)d_in[20];
    const float* W1 = (const float*)d_in[21];
    const float* b1 = (const float*)d_in[22];
    const float* W2 = (const float*)d_in[23];
    const float* b2 = (const float*)d_in[24];

    char* wsb = (char*)d_ws;
    size_t off = 0;
    auto alloc = [&](size_t bytes) -> void* {
        off = (off + 255) & ~(size_t)255;
        void* p = wsb + off; off += bytes; return p;
    };

    _Float16*  xb      = (_Float16*)alloc(M * D * 2);   // layer input x_l
    _Float16*  tb      = (_Float16*)alloc(M * D * 2);   // pre-LN accumulator
    _Float16*  hb      = (_Float16*)alloc(M * D * 2);   // post-LN1 h
    _Float16*  qkv     = (_Float16*)alloc(M * 3 * D * 2);   // [M][1536] q|k|(v unused)
    _Float16*  vT      = (_Float16*)alloc(M * D * 2);
    _Float16*  ob      = (_Float16*)alloc(M * D * 2);
    float*     biasKey = (float*)alloc(M * 4);
    _Float16*  WqkvT = (_Float16*)alloc((size_t)L * 3 * D * D * 2);
    float*     bqkv  = (float*)alloc((size_t)L * 3 * D * 4);
    _Float16*  WoT  = (_Float16*)alloc((size_t)L * D * D * 2);
    _Float16*  W1T  = (_Float16*)alloc((size_t)L * D * DFF * 2);
    _Float16*  W2T  = (_Float16*)alloc((size_t)L * DFF * D * 2);
    _Float16*  catT = (_Float16*)alloc((size_t)1024 * 256 * 2);   // padded to 1024 rows
    _Float16*  conT = (_Float16*)alloc((size_t)NCONT * 128 * 2);

    size_t need_ffh = (size_t)M * DFF * 2;
    _Float16* ffh;
    size_t offAl = (off + 255) & ~(size_t)255;
    if (offAl + need_ffh <= ws_size) ffh = (_Float16*)alloc(need_ffh);
    else ffh = (_Float16*)d_out;

    auto gemm = [&](const _Float16* A, long lda, long sA1, long sA2,
                    const _Float16* Bm, long ldb, long sB1, long sB2,
                    float* Cf, _Float16* Cb, long ldc, long sC1, long sC2,
                    const float* bias, long sb1, long sb2,
                    const _Float16* resid, _Float16* vt, int Mm, int Nn, int Kk,
                    int Z1, int Z2, float alpha, int relu, int deep) {
        dim3 gdim((Nn + 127) / 128, (Mm + 127) / 128, Z1 * Z2);
        if (deep)
            gemm_nt<1><<<gdim, 256, 0, stream>>>(A, lda, sA1, sA2, Bm, ldb, sB1, sB2,
                                                 Cf, Cb, ldc, sC1, sC2, bias, sb1, sb2,
                                                 resid, vt, Mm, Nn, Kk, Z2, alpha, relu);
        else
            gemm_nt<0><<<gdim, 256, 0, stream>>>(A, lda, sA1, sA2, Bm, ldb, sB1, sB2,
                                                 Cf, Cb, ldc, sC1, sC2, bias, sb1, sb2,
                                                 resid, vt, Mm, Nn, Kk, Z2, alpha, relu);
    };

    dim3 tb8(32, 8);
    // QKV weights concat -> [L][1536][512] NT form
    tcast_k<<<dim3(D / 32, D / 32, L), tb8, 0, stream>>>(Wq, WqkvT, D, D, (long)3 * D * D, 0);
    tcast_k<<<dim3(D / 32, D / 32, L), tb8, 0, stream>>>(Wk, WqkvT, D, D, (long)3 * D * D, D);
    tcast_k<<<dim3(D / 32, D / 32, L), tb8, 0, stream>>>(Wv, WqkvT, D, D, (long)3 * D * D, 2 * D);
    bcat_k<<<dim3((L * 1536 + 255) / 256), 256, 0, stream>>>(bq, bk, bv, bqkv, L);
    tcast_k<<<dim3(D / 32, D / 32, L), tb8, 0, stream>>>(Wo, WoT, D, D, (long)D * D, 0);
    tcast_k<<<dim3(DFF / 32, D / 32, L), tb8, 0, stream>>>(W1, W1T, D, DFF, (long)D * DFF, 0);
    tcast_k<<<dim3(D / 32, DFF / 32, L), tb8, 0, stream>>>(W2, W2T, DFF, D, (long)DFF * D, 0);
    cast_f32_f16_k<<<dim3(512), 256, 0, stream>>>(cat_table, catT, (long)NCAT * 256, (long)1024 * 256);
    cast_f32_f16_k<<<dim3(512), 256, 0, stream>>>(cont_tab, conT, (long)NCONT * 128, (long)NCONT * 128);

    embed_k<<<dim3((unsigned)M), 128, 0, stream>>>(ccat, ctime, cf0, tcat, ttime, tf0,
                                                   cat_table, pad_emb, xb, biasKey);

    for (int l = 0; l < L; l++) {
        // fused QKV projection: [M][1536]; V columns scattered to vT directly
        gemm(xb, D, 0, 0, WqkvT + (size_t)l * 3 * D * D, D, 0, 0, nullptr, qkv, 3 * D, 0, 0,
             bqkv + (size_t)l * 3 * D, 0, 0, nullptr, vT, (int)M, 3 * D, D, 1, 1, 1.f, 0, 0);

        flash_k<<<dim3(Bn * H, S / 128), 512, 0, stream>>>(qkv, vT, biasKey, ob);

        // Wo: N=512 -> grid-starved -> BK=64; tb = ob@Wo + bo + xb
        gemm(ob, D, 0, 0, WoT + (size_t)l * D * D, D, 0, 0, nullptr, tb, D, 0, 0,
             bo + l * D, 0, 0, xb, nullptr, (int)M, D, D, 1, 1, 1.f, 0, 1);
        layernorm_k<<<dim3((unsigned)M), 256, 0, stream>>>(tb, hb, ln1g + l * D, ln1b + l * D);

        // W1: grid-rich -> BK=32
        gemm(hb, D, 0, 0, W1T + (size_t)l * D * DFF, D, 0, 0, nullptr, ffh, DFF, 0, 0,
             b1 + l * DFF, 0, 0, nullptr, nullptr, (int)M, DFF, D, 1, 1, 1.f, 1, 0);
        // W2: N=512, K=2048 -> grid-starved long-K -> BK=64; tb = ffh@W2 + b2 + hb
        gemm(ffh, DFF, 0, 0, W2T + (size_t)l * DFF * D, DFF, 0, 0, nullptr, tb, D, 0, 0,
             b2 + l * D, 0, 0, hb, nullptr, (int)M, D, DFF, 1, 1, 1.f, 0, 1);
        layernorm_k<<<dim3((unsigned)M), 256, 0, stream>>>(tb, xb, ln2g + l * D, ln2b + l * D);
    }

    float* out_cat  = (float*)d_out;
    float* out_time = out_cat + (size_t)Bn * 512 * NCAT;
    float* out_f0   = out_time + (size_t)Bn * 512 * NCONT;
    gemm(xb + (size_t)512 * D, D, (long)S * D, 0,
         catT, 256, 0, 0,
         out_cat, nullptr, NCAT, (long)512 * NCAT, 0,
         nullptr, 0, 0, nullptr, nullptr, 512, NCAT, 256, Bn, 1, 1.f, 0, 0);
    // fused time/f0 projection: Z1=16 batches, Z2=2 streams (A offset +128 cols,
    // C offset one full output block)
    gemm(xb + (size_t)512 * D + 256, D, (long)S * D, 128,
         conT, 128, 0, 0,
         out_time, nullptr, NCONT, (long)512 * NCONT, (long)Bn * 512 * NCONT,
         nullptr, 0, 0, nullptr, nullptr, 512, NCONT, 128, Bn, 2, 1.f, 0, 0);
}

// Round 16
// 812.497 us; speedup vs baseline: 1.0542x; 1.0542x over previous
//
#include <hip/hip_runtime.h>

// ---------------------------------------------------------------------------
// SequenceModel: embed -> 2x transformer layer (flash attention) -> 3 projections
// All activations and the residual stream are f16 (accum f32 inside kernels).
// GEMMs: C[M,N] = alpha * A[M,K] @ B[N,K]^T (+bias[col]) (+f16 resid) (relu)
// gemm_nt<MODE>: MODE=0: BK=32, 2-buf, 32KB LDS (grid-rich shapes, 5/CU).
//                MODE=1: BK=64, 2-buf, 64KB LDS (grid-starved N=512 shapes:
//                  Wo, W2 -- 512-block grids cap at 2 blocks/CU anyway;
//                  fatter K-steps halve barrier/waitcnt overhead per MFMA).
// V transpose via LDS-tiled vtrans_k (coalesced both sides).
// flash_k: 8-wave QBLK=128, bias as MFMA C-init, in-register P exchange,
//   dbuf K/V via gload_lds.
// ---------------------------------------------------------------------------

typedef _Float16 half8 __attribute__((ext_vector_type(8)));
typedef _Float16 half4 __attribute__((ext_vector_type(4)));
typedef float f32x4 __attribute__((ext_vector_type(4)));
typedef unsigned int uint2v __attribute__((ext_vector_type(2)));
typedef unsigned int uint4v __attribute__((ext_vector_type(4)));

__device__ __forceinline__ void gl2lds16(const _Float16* g, _Float16* l) {
    __builtin_amdgcn_global_load_lds(
        (const __attribute__((address_space(1))) void*)g,
        (__attribute__((address_space(3))) void*)l, 16, 0, 0);
}

// ------------------- cast f32->f16 with zero-pad tail ----------------------
__global__ void cast_f32_f16_k(const float* __restrict__ in, _Float16* __restrict__ out,
                               long nsrc, long ntot) {
    long i = (long)blockIdx.x * blockDim.x + threadIdx.x;
    long stride = (long)gridDim.x * blockDim.x;
    for (; i < ntot; i += stride) out[i] = i < nsrc ? (_Float16)in[i] : (_Float16)0.f;
}

// ------ transpose+cast: in (Z,R,C) f32 -> out + z*zs + (rowoff+c)*R f16 ----
__global__ void tcast_k(const float* __restrict__ in, _Float16* __restrict__ out,
                        int R, int C, long zs, int rowoff) {
    __shared__ float tile[32][33];
    long z = blockIdx.z;
    const float* src = in + z * (long)R * C;
    _Float16* dst = out + z * zs + (long)rowoff * R;
    int c0 = blockIdx.x * 32, r0 = blockIdx.y * 32;
    for (int i = threadIdx.y; i < 32; i += 8)
        tile[i][threadIdx.x] = src[(long)(r0 + i) * C + c0 + threadIdx.x];
    __syncthreads();
    for (int i = threadIdx.y; i < 32; i += 8)
        dst[(long)(c0 + i) * R + r0 + threadIdx.x] = (_Float16)tile[threadIdx.x][i];
}

// --------------------------- bias concat q|k|v ------------------------------
__global__ void bcat_k(const float* __restrict__ bq, const float* __restrict__ bk,
                       const float* __restrict__ bv, float* __restrict__ out, int L) {
    int i = blockIdx.x * 256 + threadIdx.x;
    if (i >= L * 1536) return;
    int l = i / 1536, j = i - l * 1536;
    float v = j < 512 ? bq[l * 512 + j] : (j < 1024 ? bk[l * 512 + j - 512] : bv[l * 512 + j - 1024]);
    out[i] = v;
}

// -------- V transpose: qkv[...,1024+h*64+d] -> vT (B*H, hd, S) f16 ---------
__global__ void vtrans_k(const _Float16* __restrict__ qkv, _Float16* __restrict__ vT) {
    __shared__ _Float16 tile[32][33];
    int bh = blockIdx.z; int b = bh >> 3, h = bh & 7;
    int s0 = blockIdx.x * 32, d0 = blockIdx.y * 32;
    const _Float16* src = qkv + ((long)b * 1024) * 1536 + 1024 + h * 64;  // [s][d], ld=1536
    _Float16* dst = vT + (long)bh * 64 * 1024;                            // [d][s], ld=1024
    for (int i = threadIdx.y; i < 32; i += 8)
        tile[i][threadIdx.x] = src[(long)(s0 + i) * 1536 + d0 + threadIdx.x];
    __syncthreads();
    for (int i = threadIdx.y; i < 32; i += 8)
        dst[(long)(d0 + i) * 1024 + s0 + threadIdx.x] = tile[threadIdx.x][i];
}

// ------------------------------- embedding ---------------------------------
__global__ __launch_bounds__(128) void embed_k(
    const int* __restrict__ ccat, const float* __restrict__ ctime, const float* __restrict__ cf0,
    const int* __restrict__ tcat, const float* __restrict__ ttime, const float* __restrict__ tf0,
    const float* __restrict__ cat_table, const float* __restrict__ pad_emb,
    _Float16* __restrict__ xb, float* __restrict__ biasKey) {
    int t = blockIdx.x;             // token 0..16383
    int b = t >> 10, s = t & 1023;
    int j = b * 512 + (s & 511);
    int cat; float tm, f0;
    if (s < 512) { cat = ccat[j]; tm = ctime[j]; f0 = cf0[j]; }
    else         { cat = tcat[j]; tm = ttime[j]; f0 = tf0[j]; }
    bool pad = cat < 0;
    if (threadIdx.x == 0) biasKey[t] = pad ? -1e9f : 0.f;
    int c = cat < 0 ? 0 : cat;
    half4 h4;
    #pragma unroll
    for (int u = 0; u < 4; u++) {
        int d = threadIdx.x * 4 + u;   // 0..511
        float val;
        if (pad) val = pad_emb[d];
        else if (d < 256) val = cat_table[(long)c * 256 + d];
        else {
            float base = (d < 384) ? tm : f0;
            int i = (d < 384) ? (d - 256) : (d - 384);
            float ang = base / powf(1000.f, (float)i * (1.f / 128.f));
            val = (i & 1) ? cosf(ang) : sinf(ang);
        }
        h4[u] = (_Float16)val;
    }
    *(half4*)&xb[(long)t * 512 + threadIdx.x * 4] = h4;
}

// ------------------------------ layernorm (f16 in/out) ---------------------
__global__ __launch_bounds__(256) void layernorm_k(
    const _Float16* __restrict__ in, _Float16* __restrict__ out,
    const float* __restrict__ g, const float* __restrict__ beta) {
    long row = blockIdx.x;
    int tid = threadIdx.x;
    const unsigned* rw = (const unsigned*)(in + row * 512);
    unsigned wo = rw[tid];
    float v0 = (float)(_Float16)__builtin_bit_cast(_Float16, (unsigned short)(wo & 0xffff));
    float v1 = (float)(_Float16)__builtin_bit_cast(_Float16, (unsigned short)(wo >> 16));
    float s = v0 + v1, q = v0 * v0 + v1 * v1;
    #pragma unroll
    for (int o = 32; o; o >>= 1) { s += __shfl_down(s, o); q += __shfl_down(q, o); }
    __shared__ float rs[4], rq[4];
    if ((tid & 63) == 0) { rs[tid >> 6] = s; rq[tid >> 6] = q; }
    __syncthreads();
    s = rs[0] + rs[1] + rs[2] + rs[3];
    q = rq[0] + rq[1] + rq[2] + rq[3];
    float mean = s * (1.f / 512.f);
    float var = q * (1.f / 512.f) - mean * mean;
    float rstd = rsqrtf(var + 1e-5f);
    float y0 = (v0 - mean) * rstd * g[tid * 2] + beta[tid * 2];
    float y1 = (v1 - mean) * rstd * g[tid * 2 + 1] + beta[tid * 2 + 1];
    unsigned short u0 = __builtin_bit_cast(unsigned short, (_Float16)y0);
    unsigned short u1 = __builtin_bit_cast(unsigned short, (_Float16)y1);
    ((unsigned*)(out + row * 512))[tid] = (unsigned)u0 | ((unsigned)u1 << 16);
}

// ------------------------------ flash attention ----------------------------
// grid (B*H, S/128), 512 threads = 8 waves, wave w handles 16 q rows.
// KVBLK=64 dbuf via global_load_lds (XOR-slot source swizzle). Key-pad bias
// enters as the QK MFMA C-initializer. P->A-operand exchange in-register:
// cvt_pkrtz packs, permlane32_swap, ds_swizzle. exp2-domain softmax,
// defer-max THR=8 (log2), setprio around MFMA.
__global__ __launch_bounds__(512, 4) void flash_k(
    const _Float16* __restrict__ QKV, const _Float16* __restrict__ VT,
    const float* __restrict__ biasKey, _Float16* __restrict__ O) {
    const int S = 1024, D = 512, LDQ = 1536, NT = 16;
    int bh = blockIdx.x; int b = bh >> 3, h = bh & 7;
    int qt = blockIdx.y;
    int tid = threadIdx.x, w = tid >> 6, lane = tid & 63;
    int g = lane >> 4, q15 = lane & 15;

    __shared__ __align__(16) _Float16 Ks[2][64 * 64];   // [kv][d], 8x16B slots/row
    __shared__ __align__(16) _Float16 VTs[2][64 * 64];  // [d][kv]
    __shared__ __align__(16) float biasLds[1024];

    {   // bias * log2(e) (0 or -1.44e9)
        const float* bsrc = biasKey + (long)b * S;
        biasLds[tid]       = bsrc[tid] * 1.442695041f;
        biasLds[tid + 512] = bsrc[tid + 512] * 1.442695041f;
    }

    // Q fragments, pre-scaled by 0.125*log2(e)
    int qrow = qt * 128 + w * 16 + q15;
    const _Float16* qp = QKV + ((long)(b * S + qrow)) * LDQ + h * 64 + g * 8;
    half8 qf[2];
    qf[0] = *(const half8*)(qp);
    qf[1] = *(const half8*)(qp + 32);
    const _Float16 qsc = (_Float16)0.1803368801f;
    #pragma unroll
    for (int kk = 0; kk < 2; kk++)
        #pragma unroll
        for (int i = 0; i < 8; i++) qf[kk][i] *= qsc;

    const _Float16* kbase = QKV + 512 + ((long)b * S) * LDQ + h * 64;
    const _Float16* vbase = VT + (long)bh * 64 * S;

    auto stageK = [&](int buf, int kt) {
        int row = tid >> 3, p = tid & 7;
        int s = p ^ (row & 7);
        gl2lds16(kbase + (long)(kt * 64 + row) * LDQ + s * 8, &Ks[buf][tid * 8]);
    };
    auto stageV = [&](int buf, int kt) {
        int row = tid >> 3, p = tid & 7;
        int s = p ^ (row & 7);
        gl2lds16(vbase + (long)row * S + kt * 64 + s * 8, &VTs[buf][tid * 8]);
    };

    f32x4 acc_o[4];
    #pragma unroll
    for (int i = 0; i < 4; i++)
        #pragma unroll
        for (int r = 0; r < 4; r++) acc_o[i][r] = 0.f;
    float m_run = -1e30f, l_run = 0.f;
    bool gOdd = (g & 1) != 0;

    // QK^T swapped: lane owns q=q15, keys 16*mf+4*g+r; bias enters as C-init.
    auto QK = [&](int kt, f32x4 (&s)[4]) {
        #pragma unroll
        for (int mf = 0; mf < 4; mf++)
            s[mf] = *(const f32x4*)&biasLds[kt * 64 + mf * 16 + g * 4];
        int buf = kt & 1;
        __builtin_amdgcn_s_setprio(1);
        #pragma unroll
        for (int kk = 0; kk < 2; kk++)
            #pragma unroll
            for (int mf = 0; mf < 4; mf++) {
                int row = mf * 16 + q15;
                half8 kf = *(const half8*)&Ks[buf][row * 64 + (((kk * 4 + g) ^ (row & 7)) * 8)];
                s[mf] = __builtin_amdgcn_mfma_f32_16x16x32_f16(kf, qf[kk], s[mf], 0, 0, 0);
            }
        __builtin_amdgcn_s_setprio(0);
    };

    auto SMPV = [&](int kt, f32x4 (&s)[4]) {
        float t0 = fmaxf(fmaxf(s[0][0], s[0][1]), fmaxf(s[0][2], s[0][3]));
        float t1 = fmaxf(fmaxf(s[1][0], s[1][1]), fmaxf(s[1][2], s[1][3]));
        float t2 = fmaxf(fmaxf(s[2][0], s[2][1]), fmaxf(s[2][2], s[2][3]));
        float t3 = fmaxf(fmaxf(s[3][0], s[3][1]), fmaxf(s[3][2], s[3][3]));
        float mt = fmaxf(fmaxf(t0, t1), fmaxf(t2, t3));
        mt = fmaxf(mt, __shfl_xor(mt, 16));
        mt = fmaxf(mt, __shfl_xor(mt, 32));

        float rsum = 0.f;
        if (__all(mt - m_run <= 8.f)) {
            #pragma unroll
            for (int mf = 0; mf < 4; mf++)
                #pragma unroll
                for (int r = 0; r < 4; r++) {
                    float p = exp2f(s[mf][r] - m_run);
                    s[mf][r] = p; rsum += p;
                }
        } else {
            float m_new = fmaxf(m_run, mt);
            float scale = exp2f(m_run - m_new);
            #pragma unroll
            for (int mf = 0; mf < 4; mf++)
                #pragma unroll
                for (int r = 0; r < 4; r++) {
                    float p = exp2f(s[mf][r] - m_new);
                    s[mf][r] = p; rsum += p;
                }
            float sc[4];
            #pragma unroll
            for (int r = 0; r < 4; r++) sc[r] = __shfl(scale, g * 4 + r);
            #pragma unroll
            for (int nf = 0; nf < 4; nf++)
                #pragma unroll
                for (int r = 0; r < 4; r++) acc_o[nf][r] *= sc[r];
            l_run *= scale;
            m_run = m_new;
        }
        rsum += __shfl_xor(rsum, 16);
        rsum += __shfl_xor(rsum, 32);
        l_run += rsum;

        unsigned pk[4][2];
        #pragma unroll
        for (int mf = 0; mf < 4; mf++) {
            auto h0 = __builtin_amdgcn_cvt_pkrtz(s[mf][0], s[mf][1]);
            auto h1 = __builtin_amdgcn_cvt_pkrtz(s[mf][2], s[mf][3]);
            pk[mf][0] = __builtin_bit_cast(unsigned, h0);
            pk[mf][1] = __builtin_bit_cast(unsigned, h1);
        }

        int buf = kt & 1;
        #pragma unroll
        for (int kk = 0; kk < 2; kk++) {
            unsigned wA[2], wB[2];
            #pragma unroll
            for (int wi = 0; wi < 2; wi++) {
                uint2v r2 = __builtin_amdgcn_permlane32_swap(
                    pk[2 * kk][wi], pk[2 * kk + 1][wi], false, false);
                unsigned na = r2[0];
                unsigned nb = r2[1];
                unsigned sa = (unsigned)__builtin_amdgcn_ds_swizzle((int)na, 0x401F); // lane^16
                unsigned sb = (unsigned)__builtin_amdgcn_ds_swizzle((int)nb, 0x401F);
                wA[wi] = gOdd ? sb : na;
                wB[wi] = gOdd ? nb : sa;
            }
            uint4v paw;
            paw[0] = wA[0]; paw[1] = wA[1]; paw[2] = wB[0]; paw[3] = wB[1];
            half8 pa = __builtin_bit_cast(half8, paw);
            __builtin_amdgcn_s_setprio(1);
            #pragma unroll
            for (int nf = 0; nf < 4; nf++) {
                int row = nf * 16 + q15;
                half8 vf = *(const half8*)&VTs[buf][row * 64 + (((kk * 4 + g) ^ (row & 7)) * 8)];
                acc_o[nf] = __builtin_amdgcn_mfma_f32_16x16x32_f16(pa, vf, acc_o[nf], 0, 0, 0);
            }
            __builtin_amdgcn_s_setprio(0);
        }
    };

    f32x4 sA[4], sB[4];
    stageK(0, 0); stageV(0, 0); stageK(1, 1);
    __syncthreads();          // prologue stages landed (also covers biasLds)
    QK(0, sA);

    for (int t = 0; t < NT; t += 2) {
        __syncthreads();
        if (t + 2 < NT) stageK(t & 1, t + 2);
        if (t + 1 < NT) stageV((t + 1) & 1, t + 1);
        if (t + 1 < NT) QK(t + 1, sB);          // MFMA in flight over softmax(t)
        SMPV(t, sA);
        __syncthreads();
        if (t + 3 < NT) stageK((t + 1) & 1, t + 3);
        if (t + 2 < NT) stageV(t & 1, t + 2);
        if (t + 2 < NT) QK(t + 2, sA);
        SMPV(t + 1, sB);
    }

    float linv = 1.f / l_run;
    float lv[4];
    #pragma unroll
    for (int r = 0; r < 4; r++) lv[r] = __shfl(linv, g * 4 + r);
    _Float16* obase = O + ((long)(b * S + qt * 128 + w * 16)) * D + h * 64;
    #pragma unroll
    for (int nf = 0; nf < 4; nf++)
        #pragma unroll
        for (int r = 0; r < 4; r++) {
            int row = g * 4 + r;
            obase[(long)row * D + nf * 16 + q15] = (_Float16)(acc_o[nf][r] * lv[r]);
        }
}

// ------------------------------ batched NT GEMM ----------------------------
// 128x128 tile, 2-buf LDS, global_load_lds 16B, slot-swizzled, XCD-chunked.
// MODE=0: BK=32 (32KB LDS, 5 blocks/CU) for grid-rich shapes.
// MODE=1: BK=64 (64KB LDS, 2 blocks/CU) for grid-starved shapes: halves the
//         barrier/waitcnt count per unit K (32 MFMA per step).
// Requires M%128==0, K%BK==0, B rows >= ceil128(N) (pad B if needed).
template<int MODE>
__global__ __launch_bounds__(256) void gemm_nt(
    const _Float16* __restrict__ A, long lda, long sA1, long sA2,
    const _Float16* __restrict__ Bm, long ldb, long sB1, long sB2,
    float* Cf, _Float16* Cb, long ldc, long sC1, long sC2,
    const float* __restrict__ bias, long sb1, long sb2,
    const _Float16* resid,
    int M, int N, int K, int Z2, float alpha, int relu) {
    constexpr int BK = MODE ? 64 : 32;
    constexpr int SLOTS = BK / 8;           // 16B slots per row
    constexpr int LPS = (128 * BK / 8) / 256;  // loads per thread per matrix

    int z = blockIdx.z;
    int z1 = z / Z2, z2 = z - z1 * Z2;
    A  += z1 * sA1 + z2 * sA2;
    Bm += z1 * sB1 + z2 * sB2;
    long coff = z1 * sC1 + z2 * sC2;
    if (bias) bias += z1 * sb1 + z2 * sb2;

    // XCD-chunked bijective block swizzle over (y,x)
    int gx = gridDim.x;
    int nwg = gx * gridDim.y;
    int bid = blockIdx.y * gx + blockIdx.x;
    int q = nwg >> 3, r = nwg & 7;
    int xcd = bid & 7, ii = bid >> 3;
    int swz = (xcd < r ? xcd * (q + 1) : r * (q + 1) + (xcd - r) * q) + ii;
    int m0 = (swz / gx) * 128;
    int n0 = (swz % gx) * 128;

    __shared__ __align__(16) _Float16 As[2][128 * BK];
    __shared__ __align__(16) _Float16 Bs[2][128 * BK];

    int tid = threadIdx.x;
    int lane = tid & 63;
    int w = tid >> 6;
    int wr = (w >> 1) << 6;
    int wc = (w & 1) << 6;

    f32x4 acc[4][4];
    #pragma unroll
    for (int i = 0; i < 4; i++)
        #pragma unroll
        for (int jj = 0; jj < 4; jj++) { acc[i][jj][0] = 0.f; acc[i][jj][1] = 0.f; acc[i][jj][2] = 0.f; acc[i][jj][3] = 0.f; }

    int fr = lane & 15;
    int g = lane >> 4;

    auto stage = [&](int buf, int kt) {
        #pragma unroll
        for (int i = 0; i < LPS; i++) {
            int idx = tid + i * 256;
            int row = idx / SLOTS, s = idx % SLOTS;
            int sg = s ^ (row & (SLOTS - 1));
            gl2lds16(A + (long)(m0 + row) * lda + kt * BK + sg * 8, &As[buf][idx * 8]);
            gl2lds16(Bm + (long)(n0 + row) * ldb + kt * BK + sg * 8, &Bs[buf][idx * 8]);
        }
    };

    auto compute = [&](int cur) {
        #pragma unroll
        for (int kk = 0; kk < BK / 32; kk++) {
            half8 af[4], bfv[4];
            #pragma unroll
            for (int m = 0; m < 4; m++) {
                int row = wr + m * 16 + fr;
                af[m] = *(const half8*)&As[cur][row * BK + (((kk * 4 + g) ^ (row & (SLOTS - 1))) * 8)];
            }
            #pragma unroll
            for (int n = 0; n < 4; n++) {
                int row = wc + n * 16 + fr;
                bfv[n] = *(const half8*)&Bs[cur][row * BK + (((kk * 4 + g) ^ (row & (SLOTS - 1))) * 8)];
            }
            #pragma unroll
            for (int m = 0; m < 4; m++)
                #pragma unroll
                for (int n = 0; n < 4; n++)
                    acc[m][n] = __builtin_amdgcn_mfma_f32_16x16x32_f16(af[m], bfv[n], acc[m][n], 0, 0, 0);
        }
    };

    int nk = K / BK;
    stage(0, 0);
    for (int t = 0; t < nk; ++t) {
        __builtin_amdgcn_s_barrier();            // readers of buf[(t+1)&1] done
        if (t + 1 < nk) {
            stage((t + 1) & 1, t + 1);           // issue next stage early
            if constexpr (MODE == 0)
                asm volatile("s_waitcnt vmcnt(4)" ::: "memory");   // stage(t) landed
            else
                asm volatile("s_waitcnt vmcnt(8)" ::: "memory");
        } else {
            asm volatile("s_waitcnt vmcnt(0)" ::: "memory");
        }
        __builtin_amdgcn_s_barrier();            // all waves' stage(t) landed
        __builtin_amdgcn_sched_barrier(0);
        compute(t & 1);
    }

    int fq = lane >> 4;
    #pragma unroll
    for (int m = 0; m < 4; m++) {
        #pragma unroll
        for (int jj = 0; jj < 4; jj++) {
            long row = m0 + wr + m * 16 + fq * 4 + jj;
            #pragma unroll
            for (int n = 0; n < 4; n++) {
                int col = n0 + wc + n * 16 + fr;
                if (col < N) {
                    float v = acc[m][n][jj] * alpha;
                    if (bias) v += bias[col];
                    long o = coff + row * ldc + col;
                    if (resid) v += (float)resid[o];
                    if (relu) v = fmaxf(v, 0.f);
                    if (Cf) Cf[o] = v;
                    if (Cb) Cb[o] = (_Float16)v;
                }
            }
        }
    }
}

// ---------------------------------------------------------------------------
extern "C" void kernel_launch(void* const* d_in, const int* in_sizes, int n_in,
                              void* d_out, int out_size, void* d_ws, size_t ws_size,
                              hipStream_t stream) {
    const int Bn = 16, S = 1024, D = 512, H = 8, L = 2, DFF = 2048, NCAT = 1000, NCONT = 2048;
    const long M = (long)Bn * S;

    const int*   ccat      = (const int*)d_in[0];
    const float* ctime     = (const float*)d_in[1];
    const float* cf0       = (const float*)d_in[2];
    const int*   tcat      = (const int*)d_in[3];
    const float* ttime     = (const float*)d_in[4];
    const float* tf0       = (const float*)d_in[5];
    const float* cat_table = (const float*)d_in[6];
    const float* cont_tab  = (const float*)d_in[7];
    const float* pad_emb   = (const float*)d_in[8];
    const float* Wq = (const float*)d_in[9];
    const float* bq = (const float*)d_in[10];
    const float* Wk = (const float*)d_in[11];
    const float* bk = (const float*)d_in[12];
    const float* Wv = (const float*)d_in[13];
    const float* bv = (const float*)d_in[14];
    const float* Wo = (const float*)d_in[15];
    const float* bo = (const float*)d_in[16];
    const float* ln1g = (const float*)d_in[17];
    const float* ln1b = (const float*)d_in[18];
    const float* ln2g = (const float*)d_in[19];
    const float* ln2b = (const float*)d_in[20];
    const float* W1 = (const float*)d_in[21];
    const float* b1 = (const float*)d_in[22];
    const float* W2 = (const float*)d_in[23];
    const float* b2 = (const float*)d_in[24];

    char* wsb = (char*)d_ws;
    size_t off = 0;
    auto alloc = [&](size_t bytes) -> void* {
        off = (off + 255) & ~(size_t)255;
        void* p = wsb + off; off += bytes; return p;
    };

    _Float16*  xb      = (_Float16*)alloc(M * D * 2);   // layer input x_l
    _Float16*  tb      = (_Float16*)alloc(M * D * 2);   // pre-LN accumulator
    _Float16*  hb      = (_Float16*)alloc(M * D * 2);   // post-LN1 h
    _Float16*  qkv     = (_Float16*)alloc(M * 3 * D * 2);   // [M][1536] q|k|v
    _Float16*  vT      = (_Float16*)alloc(M * D * 2);
    _Float16*  ob      = (_Float16*)alloc(M * D * 2);
    float*     biasKey = (float*)alloc(M * 4);
    _Float16*  WqkvT = (_Float16*)alloc((size_t)L * 3 * D * D * 2);
    float*     bqkv  = (float*)alloc((size_t)L * 3 * D * 4);
    _Float16*  WoT  = (_Float16*)alloc((size_t)L * D * D * 2);
    _Float16*  W1T  = (_Float16*)alloc((size_t)L * D * DFF * 2);
    _Float16*  W2T  = (_Float16*)alloc((size_t)L * DFF * D * 2);
    _Float16*  catT = (_Float16*)alloc((size_t)1024 * 256 * 2);   // padded to 1024 rows
    _Float16*  conT = (_Float16*)alloc((size_t)NCONT * 128 * 2);

    size_t need_ffh = (size_t)M * DFF * 2;
    _Float16* ffh;
    size_t offAl = (off + 255) & ~(size_t)255;
    if (offAl + need_ffh <= ws_size) ffh = (_Float16*)alloc(need_ffh);
    else ffh = (_Float16*)d_out;

    auto gemm = [&](const _Float16* A, long lda, long sA1, long sA2,
                    const _Float16* Bm, long ldb, long sB1, long sB2,
                    float* Cf, _Float16* Cb, long ldc, long sC1, long sC2,
                    const float* bias, long sb1, long sb2,
                    const _Float16* resid, int Mm, int Nn, int Kk,
                    int Z1, int Z2, float alpha, int relu, int deep) {
        dim3 gdim((Nn + 127) / 128, (Mm + 127) / 128, Z1 * Z2);
        if (deep)
            gemm_nt<1><<<gdim, 256, 0, stream>>>(A, lda, sA1, sA2, Bm, ldb, sB1, sB2,
                                                 Cf, Cb, ldc, sC1, sC2, bias, sb1, sb2,
                                                 resid, Mm, Nn, Kk, Z2, alpha, relu);
        else
            gemm_nt<0><<<gdim, 256, 0, stream>>>(A, lda, sA1, sA2, Bm, ldb, sB1, sB2,
                                                 Cf, Cb, ldc, sC1, sC2, bias, sb1, sb2,
                                                 resid, Mm, Nn, Kk, Z2, alpha, relu);
    };

    dim3 tb8(32, 8);
    // QKV weights concat -> [L][1536][512] NT form
    tcast_k<<<dim3(D / 32, D / 32, L), tb8, 0, stream>>>(Wq, WqkvT, D, D, (long)3 * D * D, 0);
    tcast_k<<<dim3(D / 32, D / 32, L), tb8, 0, stream>>>(Wk, WqkvT, D, D, (long)3 * D * D, D);
    tcast_k<<<dim3(D / 32, D / 32, L), tb8, 0, stream>>>(Wv, WqkvT, D, D, (long)3 * D * D, 2 * D);
    bcat_k<<<dim3((L * 1536 + 255) / 256), 256, 0, stream>>>(bq, bk, bv, bqkv, L);
    tcast_k<<<dim3(D / 32, D / 32, L), tb8, 0, stream>>>(Wo, WoT, D, D, (long)D * D, 0);
    tcast_k<<<dim3(DFF / 32, D / 32, L), tb8, 0, stream>>>(W1, W1T, D, DFF, (long)D * DFF, 0);
    tcast_k<<<dim3(D / 32, DFF / 32, L), tb8, 0, stream>>>(W2, W2T, DFF, D, (long)DFF * D, 0);
    cast_f32_f16_k<<<dim3(512), 256, 0, stream>>>(cat_table, catT, (long)NCAT * 256, (long)1024 * 256);
    cast_f32_f16_k<<<dim3(512), 256, 0, stream>>>(cont_tab, conT, (long)NCONT * 128, (long)NCONT * 128);

    embed_k<<<dim3((unsigned)M), 128, 0, stream>>>(ccat, ctime, cf0, tcat, ttime, tf0,
                                                   cat_table, pad_emb, xb, biasKey);

    for (int l = 0; l < L; l++) {
        // fused QKV projection: [M][1536] (grid-rich: BK=32)
        gemm(xb, D, 0, 0, WqkvT + (size_t)l * 3 * D * D, D, 0, 0, nullptr, qkv, 3 * D, 0, 0,
             bqkv + (size_t)l * 3 * D, 0, 0, nullptr, (int)M, 3 * D, D, 1, 1, 1.f, 0, 0);
        vtrans_k<<<dim3(32, 2, Bn * H), tb8, 0, stream>>>(qkv, vT);

        flash_k<<<dim3(Bn * H, S / 128), 512, 0, stream>>>(qkv, vT, biasKey, ob);

        // Wo: N=512 -> grid-starved -> BK=64; tb = ob@Wo + bo + xb
        gemm(ob, D, 0, 0, WoT + (size_t)l * D * D, D, 0, 0, nullptr, tb, D, 0, 0,
             bo + l * D, 0, 0, xb, (int)M, D, D, 1, 1, 1.f, 0, 1);
        layernorm_k<<<dim3((unsigned)M), 256, 0, stream>>>(tb, hb, ln1g + l * D, ln1b + l * D);

        // W1: grid-rich -> BK=32
        gemm(hb, D, 0, 0, W1T + (size_t)l * D * DFF, D, 0, 0, nullptr, ffh, DFF, 0, 0,
             b1 + l * DFF, 0, 0, nullptr, (int)M, DFF, D, 1, 1, 1.f, 1, 0);
        // W2: N=512, K=2048 -> grid-starved long-K -> BK=64; tb = ffh@W2 + b2 + hb
        gemm(ffh, DFF, 0, 0, W2T + (size_t)l * DFF * D, DFF, 0, 0, nullptr, tb, D, 0, 0,
             b2 + l * D, 0, 0, hb, (int)M, D, DFF, 1, 1, 1.f, 0, 1);
        layernorm_k<<<dim3((unsigned)M), 256, 0, stream>>>(tb, xb, ln2g + l * D, ln2b + l * D);
    }

    float* out_cat  = (float*)d_out;
    float* out_time = out_cat + (size_t)Bn * 512 * NCAT;
    float* out_f0   = out_time + (size_t)Bn * 512 * NCONT;
    gemm(xb + (size_t)512 * D, D, (long)S * D, 0,
         catT, 256, 0, 0,
         out_cat, nullptr, NCAT, (long)512 * NCAT, 0,
         nullptr, 0, 0, nullptr, 512, NCAT, 256, Bn, 1, 1.f, 0, 0);
    // fused time/f0 projection: Z1=16 batches, Z2=2 streams (A offset +128 cols,
    // C offset one full output block)
    gemm(xb + (size_t)512 * D + 256, D, (long)S * D, 128,
         conT, 128, 0, 0,
         out_time, nullptr, NCONT, (long)512 * NCONT, (long)Bn * 512 * NCONT,
         nullptr, 0, 0, nullptr, 512, NCONT, 128, Bn, 2, 1.f, 0, 0);
}

// Round 17
// 800.537 us; speedup vs baseline: 1.0699x; 1.0149x over previous
//
#include <hip/hip_runtime.h>

// ---------------------------------------------------------------------------
// SequenceModel: embed -> 2x transformer layer (flash attention) -> 3 projections
// All activations and the residual stream are f16 (accum f32 inside kernels).
// GEMMs: C[M,N] = alpha * A[M,K] @ B[N,K]^T (+bias[col]) (+f16 resid) (relu)
// gemm_nt<MODE>: MODE=0: BK=32, 2-buf, 32KB LDS (grid-rich shapes, 5/CU).
//                MODE=1: BK=64, 2-buf, 64KB LDS (grid-starved N=512 shapes).
// flash_k: 8-wave QBLK=128, KVBLK=128 (8 tiles, 1 barrier/tile), bias as MFMA
//   C-init, in-register P exchange, dbuf K/V via gload_lds, 68KB LDS.
// layernorm_k: wave-per-row, shfl-only reduction, no LDS.
// ---------------------------------------------------------------------------

typedef _Float16 half8 __attribute__((ext_vector_type(8)));
typedef _Float16 half4 __attribute__((ext_vector_type(4)));
typedef float f32x4 __attribute__((ext_vector_type(4)));
typedef unsigned int uint2v __attribute__((ext_vector_type(2)));
typedef unsigned int uint4v __attribute__((ext_vector_type(4)));

__device__ __forceinline__ void gl2lds16(const _Float16* g, _Float16* l) {
    __builtin_amdgcn_global_load_lds(
        (const __attribute__((address_space(1))) void*)g,
        (__attribute__((address_space(3))) void*)l, 16, 0, 0);
}

// ------------------- cast f32->f16 with zero-pad tail ----------------------
__global__ void cast_f32_f16_k(const float* __restrict__ in, _Float16* __restrict__ out,
                               long nsrc, long ntot) {
    long i = (long)blockIdx.x * blockDim.x + threadIdx.x;
    long stride = (long)gridDim.x * blockDim.x;
    for (; i < ntot; i += stride) out[i] = i < nsrc ? (_Float16)in[i] : (_Float16)0.f;
}

// ------ transpose+cast: in (Z,R,C) f32 -> out + z*zs + (rowoff+c)*R f16 ----
__global__ void tcast_k(const float* __restrict__ in, _Float16* __restrict__ out,
                        int R, int C, long zs, int rowoff) {
    __shared__ float tile[32][33];
    long z = blockIdx.z;
    const float* src = in + z * (long)R * C;
    _Float16* dst = out + z * zs + (long)rowoff * R;
    int c0 = blockIdx.x * 32, r0 = blockIdx.y * 32;
    for (int i = threadIdx.y; i < 32; i += 8)
        tile[i][threadIdx.x] = src[(long)(r0 + i) * C + c0 + threadIdx.x];
    __syncthreads();
    for (int i = threadIdx.y; i < 32; i += 8)
        dst[(long)(c0 + i) * R + r0 + threadIdx.x] = (_Float16)tile[threadIdx.x][i];
}

// --------------------------- bias concat q|k|v ------------------------------
__global__ void bcat_k(const float* __restrict__ bq, const float* __restrict__ bk,
                       const float* __restrict__ bv, float* __restrict__ out, int L) {
    int i = blockIdx.x * 256 + threadIdx.x;
    if (i >= L * 1536) return;
    int l = i / 1536, j = i - l * 1536;
    float v = j < 512 ? bq[l * 512 + j] : (j < 1024 ? bk[l * 512 + j - 512] : bv[l * 512 + j - 1024]);
    out[i] = v;
}

// -------- V transpose: qkv[...,1024+h*64+d] -> vT (B*H, hd, S) f16 ---------
__global__ void vtrans_k(const _Float16* __restrict__ qkv, _Float16* __restrict__ vT) {
    __shared__ _Float16 tile[32][33];
    int bh = blockIdx.z; int b = bh >> 3, h = bh & 7;
    int s0 = blockIdx.x * 32, d0 = blockIdx.y * 32;
    const _Float16* src = qkv + ((long)b * 1024) * 1536 + 1024 + h * 64;  // [s][d], ld=1536
    _Float16* dst = vT + (long)bh * 64 * 1024;                            // [d][s], ld=1024
    for (int i = threadIdx.y; i < 32; i += 8)
        tile[i][threadIdx.x] = src[(long)(s0 + i) * 1536 + d0 + threadIdx.x];
    __syncthreads();
    for (int i = threadIdx.y; i < 32; i += 8)
        dst[(long)(d0 + i) * 1024 + s0 + threadIdx.x] = tile[threadIdx.x][i];
}

// ------------------------------- embedding ---------------------------------
__global__ __launch_bounds__(128) void embed_k(
    const int* __restrict__ ccat, const float* __restrict__ ctime, const float* __restrict__ cf0,
    const int* __restrict__ tcat, const float* __restrict__ ttime, const float* __restrict__ tf0,
    const float* __restrict__ cat_table, const float* __restrict__ pad_emb,
    _Float16* __restrict__ xb, float* __restrict__ biasKey) {
    int t = blockIdx.x;             // token 0..16383
    int b = t >> 10, s = t & 1023;
    int j = b * 512 + (s & 511);
    int cat; float tm, f0;
    if (s < 512) { cat = ccat[j]; tm = ctime[j]; f0 = cf0[j]; }
    else         { cat = tcat[j]; tm = ttime[j]; f0 = tf0[j]; }
    bool pad = cat < 0;
    if (threadIdx.x == 0) biasKey[t] = pad ? -1e9f : 0.f;
    int c = cat < 0 ? 0 : cat;
    half4 h4;
    #pragma unroll
    for (int u = 0; u < 4; u++) {
        int d = threadIdx.x * 4 + u;   // 0..511
        float val;
        if (pad) val = pad_emb[d];
        else if (d < 256) val = cat_table[(long)c * 256 + d];
        else {
            float base = (d < 384) ? tm : f0;
            int i = (d < 384) ? (d - 256) : (d - 384);
            float ang = base / powf(1000.f, (float)i * (1.f / 128.f));
            val = (i & 1) ? cosf(ang) : sinf(ang);
        }
        h4[u] = (_Float16)val;
    }
    *(half4*)&xb[(long)t * 512 + threadIdx.x * 4] = h4;
}

// --------------------- layernorm (f16 in/out, wave-per-row) ----------------
// 256 threads = 4 waves; wave handles one row of 512 (8 f16 per lane).
__global__ __launch_bounds__(256) void layernorm_k(
    const _Float16* __restrict__ in, _Float16* __restrict__ out,
    const float* __restrict__ g, const float* __restrict__ beta) {
    int wv = threadIdx.x >> 6, lane = threadIdx.x & 63;
    long row = (long)blockIdx.x * 4 + wv;
    half8 hv = *(const half8*)(in + row * 512 + lane * 8);
    float v[8];
    float s = 0.f, q = 0.f;
    #pragma unroll
    for (int u = 0; u < 8; u++) {
        v[u] = (float)hv[u];
        s += v[u];
        q += v[u] * v[u];
    }
    #pragma unroll
    for (int o = 32; o; o >>= 1) { s += __shfl_xor(s, o); q += __shfl_xor(q, o); }
    float mean = s * (1.f / 512.f);
    float var = q * (1.f / 512.f) - mean * mean;
    float rstd = rsqrtf(var + 1e-5f);
    half8 hy;
    #pragma unroll
    for (int u = 0; u < 8; u++) {
        float y = (v[u] - mean) * rstd * g[lane * 8 + u] + beta[lane * 8 + u];
        hy[u] = (_Float16)y;
    }
    *(half8*)(out + row * 512 + lane * 8) = hy;
}

// ------------------------------ flash attention ----------------------------
// grid (B*H, S/128), 512 threads = 8 waves, wave w handles 16 q rows.
// KVBLK=128 (8 tiles): one barrier per tile; K/V dbuf via global_load_lds
// (XOR-slot source swizzle, linear LDS dest). Key-pad bias enters as the QK
// MFMA C-initializer. P->A-operand exchange in-register (cvt_pkrtz,
// permlane32_swap, ds_swizzle lane^16). exp2-domain softmax, defer-max THR=8.
__global__ __launch_bounds__(512, 4) void flash_k(
    const _Float16* __restrict__ QKV, const _Float16* __restrict__ VT,
    const float* __restrict__ biasKey, _Float16* __restrict__ O) {
    const int S = 1024, D = 512, LDQ = 1536, NT = 8;
    int bh = blockIdx.x; int b = bh >> 3, h = bh & 7;
    int qt = blockIdx.y;
    int tid = threadIdx.x, w = tid >> 6, lane = tid & 63;
    int g = lane >> 4, q15 = lane & 15;

    __shared__ __align__(16) _Float16 Ks[2][128 * 64];   // [kv][d], 8x16B slots/row
    __shared__ __align__(16) _Float16 VTs[2][64 * 128];  // [d][kv], 16 slots/row
    __shared__ __align__(16) float biasLds[1024];

    {   // bias * log2(e) (0 or -1.44e9)
        const float* bsrc = biasKey + (long)b * S;
        biasLds[tid]       = bsrc[tid] * 1.442695041f;
        biasLds[tid + 512] = bsrc[tid + 512] * 1.442695041f;
    }

    // Q fragments, pre-scaled by 0.125*log2(e)
    int qrow = qt * 128 + w * 16 + q15;
    const _Float16* qp = QKV + ((long)(b * S + qrow)) * LDQ + h * 64 + g * 8;
    half8 qf[2];
    qf[0] = *(const half8*)(qp);
    qf[1] = *(const half8*)(qp + 32);
    const _Float16 qsc = (_Float16)0.1803368801f;
    #pragma unroll
    for (int kk = 0; kk < 2; kk++)
        #pragma unroll
        for (int i = 0; i < 8; i++) qf[kk][i] *= qsc;

    const _Float16* kbase = QKV + 512 + ((long)b * S) * LDQ + h * 64;
    const _Float16* vbase = VT + (long)bh * 64 * S;

    // stage one 128-kv tile: K = 128 rows x 8 slots, V = 64 rows x 16 slots.
    auto stageK = [&](int buf, int kt) {
        #pragma unroll
        for (int i = 0; i < 2; i++) {
            int idx = tid + i * 512;            // 0..1023
            int row = idx >> 3, p = idx & 7;
            int s = p ^ (row & 7);
            gl2lds16(kbase + (long)(kt * 128 + row) * LDQ + s * 8, &Ks[buf][idx * 8]);
        }
    };
    auto stageV = [&](int buf, int kt) {
        #pragma unroll
        for (int i = 0; i < 2; i++) {
            int idx = tid + i * 512;            // 0..1023
            int row = idx >> 4, p = idx & 15;
            int s = p ^ (row & 15);
            gl2lds16(vbase + (long)row * S + kt * 128 + s * 8, &VTs[buf][idx * 8]);
        }
    };

    f32x4 acc_o[4];
    #pragma unroll
    for (int i = 0; i < 4; i++)
        #pragma unroll
        for (int r = 0; r < 4; r++) acc_o[i][r] = 0.f;
    float m_run = -1e30f, l_run = 0.f;
    bool gOdd = (g & 1) != 0;

    f32x4 s[8];
    stageK(0, 0); stageV(0, 0);
    __syncthreads();          // prologue stage landed (also covers biasLds)

    for (int t = 0; t < NT; t++) {
        if (t) __syncthreads();   // stage(t) landed; buf^1 reads of t-1 done
        int buf = t & 1;
        if (t + 1 < NT) { stageK(buf ^ 1, t + 1); stageV(buf ^ 1, t + 1); }

        // QK^T swapped: lane owns q=q15, key = t*128 + 16*mf + 4*g + r.
        // Bias enters as the MFMA C-initializer.
        #pragma unroll
        for (int mf = 0; mf < 8; mf++)
            s[mf] = *(const f32x4*)&biasLds[t * 128 + mf * 16 + g * 4];
        __builtin_amdgcn_s_setprio(1);
        #pragma unroll
        for (int kk = 0; kk < 2; kk++)
            #pragma unroll
            for (int mf = 0; mf < 8; mf++) {
                int row = mf * 16 + q15;
                half8 kf = *(const half8*)&Ks[buf][row * 64 + (((kk * 4 + g) ^ (row & 7)) * 8)];
                s[mf] = __builtin_amdgcn_mfma_f32_16x16x32_f16(kf, qf[kk], s[mf], 0, 0, 0);
            }
        __builtin_amdgcn_s_setprio(0);

        // row max over 32 scores
        float mt = -1e30f;
        #pragma unroll
        for (int mf = 0; mf < 8; mf++) {
            float a = fmaxf(fmaxf(s[mf][0], s[mf][1]), fmaxf(s[mf][2], s[mf][3]));
            mt = fmaxf(mt, a);
        }
        mt = fmaxf(mt, __shfl_xor(mt, 16));
        mt = fmaxf(mt, __shfl_xor(mt, 32));

        float rsum = 0.f;
        if (__all(mt - m_run <= 8.f)) {
            #pragma unroll
            for (int mf = 0; mf < 8; mf++)
                #pragma unroll
                for (int r = 0; r < 4; r++) {
                    float p = exp2f(s[mf][r] - m_run);
                    s[mf][r] = p; rsum += p;
                }
        } else {
            float m_new = fmaxf(m_run, mt);
            float scale = exp2f(m_run - m_new);
            #pragma unroll
            for (int mf = 0; mf < 8; mf++)
                #pragma unroll
                for (int r = 0; r < 4; r++) {
                    float p = exp2f(s[mf][r] - m_new);
                    s[mf][r] = p; rsum += p;
                }
            float sc[4];
            #pragma unroll
            for (int r = 0; r < 4; r++) sc[r] = __shfl(scale, g * 4 + r);
            #pragma unroll
            for (int nf = 0; nf < 4; nf++)
                #pragma unroll
                for (int r = 0; r < 4; r++) acc_o[nf][r] *= sc[r];
            l_run *= scale;
            m_run = m_new;
        }
        rsum += __shfl_xor(rsum, 16);
        rsum += __shfl_xor(rsum, 32);
        l_run += rsum;

        // pack P: pk[mf][wi] = f16x2 of (r=2wi, 2wi+1)
        unsigned pk[8][2];
        #pragma unroll
        for (int mf = 0; mf < 8; mf++) {
            auto h0 = __builtin_amdgcn_cvt_pkrtz(s[mf][0], s[mf][1]);
            auto h1 = __builtin_amdgcn_cvt_pkrtz(s[mf][2], s[mf][3]);
            pk[mf][0] = __builtin_bit_cast(unsigned, h0);
            pk[mf][1] = __builtin_bit_cast(unsigned, h1);
        }

        // PV: O[16q][64d] += P[16][128] @ V[128][64]; A-operand in-register.
        // dst lane (q15,g), kk=0..3: mf = 2kk+(g>>1); words from g'=2(g&1)(+1).
        #pragma unroll
        for (int kk = 0; kk < 4; kk++) {
            unsigned wA[2], wB[2];
            #pragma unroll
            for (int wi = 0; wi < 2; wi++) {
                uint2v r2 = __builtin_amdgcn_permlane32_swap(
                    pk[2 * kk][wi], pk[2 * kk + 1][wi], false, false);
                unsigned na = r2[0];
                unsigned nb = r2[1];
                unsigned sa = (unsigned)__builtin_amdgcn_ds_swizzle((int)na, 0x401F); // lane^16
                unsigned sb = (unsigned)__builtin_amdgcn_ds_swizzle((int)nb, 0x401F);
                wA[wi] = gOdd ? sb : na;
                wB[wi] = gOdd ? nb : sa;
            }
            uint4v paw;
            paw[0] = wA[0]; paw[1] = wA[1]; paw[2] = wB[0]; paw[3] = wB[1];
            half8 pa = __builtin_bit_cast(half8, paw);
            __builtin_amdgcn_s_setprio(1);
            #pragma unroll
            for (int nf = 0; nf < 4; nf++) {
                int row = nf * 16 + q15;
                half8 vf = *(const half8*)&VTs[buf][row * 128 + (((kk * 4 + g) ^ (row & 15)) * 8)];
                acc_o[nf] = __builtin_amdgcn_mfma_f32_16x16x32_f16(pa, vf, acc_o[nf], 0, 0, 0);
            }
            __builtin_amdgcn_s_setprio(0);
        }
    }

    float linv = 1.f / l_run;
    float lv[4];
    #pragma unroll
    for (int r = 0; r < 4; r++) lv[r] = __shfl(linv, g * 4 + r);
    _Float16* obase = O + ((long)(b * S + qt * 128 + w * 16)) * D + h * 64;
    #pragma unroll
    for (int nf = 0; nf < 4; nf++)
        #pragma unroll
        for (int r = 0; r < 4; r++) {
            int row = g * 4 + r;
            obase[(long)row * D + nf * 16 + q15] = (_Float16)(acc_o[nf][r] * lv[r]);
        }
}

// ------------------------------ batched NT GEMM ----------------------------
// 128x128 tile, 2-buf LDS, global_load_lds 16B, slot-swizzled, XCD-chunked.
// MODE=0: BK=32 (32KB LDS, 5 blocks/CU) for grid-rich shapes.
// MODE=1: BK=64 (64KB LDS, 2 blocks/CU) for grid-starved shapes.
// Requires M%128==0, K%BK==0, B rows >= ceil128(N) (pad B if needed).
template<int MODE>
__global__ __launch_bounds__(256) void gemm_nt(
    const _Float16* __restrict__ A, long lda, long sA1, long sA2,
    const _Float16* __restrict__ Bm, long ldb, long sB1, long sB2,
    float* Cf, _Float16* Cb, long ldc, long sC1, long sC2,
    const float* __restrict__ bias, long sb1, long sb2,
    const _Float16* resid,
    int M, int N, int K, int Z2, float alpha, int relu) {
    constexpr int BK = MODE ? 64 : 32;
    constexpr int SLOTS = BK / 8;           // 16B slots per row
    constexpr int LPS = (128 * BK / 8) / 256;  // loads per thread per matrix

    int z = blockIdx.z;
    int z1 = z / Z2, z2 = z - z1 * Z2;
    A  += z1 * sA1 + z2 * sA2;
    Bm += z1 * sB1 + z2 * sB2;
    long coff = z1 * sC1 + z2 * sC2;
    if (bias) bias += z1 * sb1 + z2 * sb2;

    // XCD-chunked bijective block swizzle over (y,x)
    int gx = gridDim.x;
    int nwg = gx * gridDim.y;
    int bid = blockIdx.y * gx + blockIdx.x;
    int q = nwg >> 3, r = nwg & 7;
    int xcd = bid & 7, ii = bid >> 3;
    int swz = (xcd < r ? xcd * (q + 1) : r * (q + 1) + (xcd - r) * q) + ii;
    int m0 = (swz / gx) * 128;
    int n0 = (swz % gx) * 128;

    __shared__ __align__(16) _Float16 As[2][128 * BK];
    __shared__ __align__(16) _Float16 Bs[2][128 * BK];

    int tid = threadIdx.x;
    int lane = tid & 63;
    int w = tid >> 6;
    int wr = (w >> 1) << 6;
    int wc = (w & 1) << 6;

    f32x4 acc[4][4];
    #pragma unroll
    for (int i = 0; i < 4; i++)
        #pragma unroll
        for (int jj = 0; jj < 4; jj++) { acc[i][jj][0] = 0.f; acc[i][jj][1] = 0.f; acc[i][jj][2] = 0.f; acc[i][jj][3] = 0.f; }

    int fr = lane & 15;
    int g = lane >> 4;

    auto stage = [&](int buf, int kt) {
        #pragma unroll
        for (int i = 0; i < LPS; i++) {
            int idx = tid + i * 256;
            int row = idx / SLOTS, s = idx % SLOTS;
            int sg = s ^ (row & (SLOTS - 1));
            gl2lds16(A + (long)(m0 + row) * lda + kt * BK + sg * 8, &As[buf][idx * 8]);
            gl2lds16(Bm + (long)(n0 + row) * ldb + kt * BK + sg * 8, &Bs[buf][idx * 8]);
        }
    };

    auto compute = [&](int cur) {
        #pragma unroll
        for (int kk = 0; kk < BK / 32; kk++) {
            half8 af[4], bfv[4];
            #pragma unroll
            for (int m = 0; m < 4; m++) {
                int row = wr + m * 16 + fr;
                af[m] = *(const half8*)&As[cur][row * BK + (((kk * 4 + g) ^ (row & (SLOTS - 1))) * 8)];
            }
            #pragma unroll
            for (int n = 0; n < 4; n++) {
                int row = wc + n * 16 + fr;
                bfv[n] = *(const half8*)&Bs[cur][row * BK + (((kk * 4 + g) ^ (row & (SLOTS - 1))) * 8)];
            }
            #pragma unroll
            for (int m = 0; m < 4; m++)
                #pragma unroll
                for (int n = 0; n < 4; n++)
                    acc[m][n] = __builtin_amdgcn_mfma_f32_16x16x32_f16(af[m], bfv[n], acc[m][n], 0, 0, 0);
        }
    };

    int nk = K / BK;
    stage(0, 0);
    for (int t = 0; t < nk; ++t) {
        __builtin_amdgcn_s_barrier();            // readers of buf[(t+1)&1] done
        if (t + 1 < nk) {
            stage((t + 1) & 1, t + 1);           // issue next stage early
            if constexpr (MODE == 0)
                asm volatile("s_waitcnt vmcnt(4)" ::: "memory");   // stage(t) landed
            else
                asm volatile("s_waitcnt vmcnt(8)" ::: "memory");
        } else {
            asm volatile("s_waitcnt vmcnt(0)" ::: "memory");
        }
        __builtin_amdgcn_s_barrier();            // all waves' stage(t) landed
        __builtin_amdgcn_sched_barrier(0);
        compute(t & 1);
    }

    int fq = lane >> 4;
    #pragma unroll
    for (int m = 0; m < 4; m++) {
        #pragma unroll
        for (int jj = 0; jj < 4; jj++) {
            long row = m0 + wr + m * 16 + fq * 4 + jj;
            #pragma unroll
            for (int n = 0; n < 4; n++) {
                int col = n0 + wc + n * 16 + fr;
                if (col < N) {
                    float v = acc[m][n][jj] * alpha;
                    if (bias) v += bias[col];
                    long o = coff + row * ldc + col;
                    if (resid) v += (float)resid[o];
                    if (relu) v = fmaxf(v, 0.f);
                    if (Cf) Cf[o] = v;
                    if (Cb) Cb[o] = (_Float16)v;
                }
            }
        }
    }
}

// ---------------------------------------------------------------------------
extern "C" void kernel_launch(void* const* d_in, const int* in_sizes, int n_in,
                              void* d_out, int out_size, void* d_ws, size_t ws_size,
                              hipStream_t stream) {
    const int Bn = 16, S = 1024, D = 512, H = 8, L = 2, DFF = 2048, NCAT = 1000, NCONT = 2048;
    const long M = (long)Bn * S;

    const int*   ccat      = (const int*)d_in[0];
    const float* ctime     = (const float*)d_in[1];
    const float* cf0       = (const float*)d_in[2];
    const int*   tcat      = (const int*)d_in[3];
    const float* ttime     = (const float*)d_in[4];
    const float* tf0       = (const float*)d_in[5];
    const float* cat_table = (const float*)d_in[6];
    const float* cont_tab  = (const float*)d_in[7];
    const float* pad_emb   = (const float*)d_in[8];
    const float* Wq = (const float*)d_in[9];
    const float* bq = (const float*)d_in[10];
    const float* Wk = (const float*)d_in[11];
    const float* bk = (const float*)d_in[12];
    const float* Wv = (const float*)d_in[13];
    const float* bv = (const float*)d_in[14];
    const float* Wo = (const float*)d_in[15];
    const float* bo = (const float*)d_in[16];
    const float* ln1g = (const float*)d_in[17];
    const float* ln1b = (const float*)d_in[18];
    const float* ln2g = (const float*)d_in[19];
    const float* ln2b = (const float*)d_in[20];
    const float* W1 = (const float*)d_in[21];
    const float* b1 = (const float*)d_in[22];
    const float* W2 = (const float*)d_in[23];
    const float* b2 = (const float*)d_in[24];

    char* wsb = (char*)d_ws;
    size_t off = 0;
    auto alloc = [&](size_t bytes) -> void* {
        off = (off + 255) & ~(size_t)255;
        void* p = wsb + off; off += bytes; return p;
    };

    _Float16*  xb      = (_Float16*)alloc(M * D * 2);   // layer input x_l
    _Float16*  tb      = (_Float16*)alloc(M * D * 2);   // pre-LN accumulator
    _Float16*  hb      = (_Float16*)alloc(M * D * 2);   // post-LN1 h
    _Float16*  qkv     = (_Float16*)alloc(M * 3 * D * 2);   // [M][1536] q|k|v
    _Float16*  vT      = (_Float16*)alloc(M * D * 2);
    _Float16*  ob      = (_Float16*)alloc(M * D * 2);
    float*     biasKey = (float*)alloc(M * 4);
    _Float16*  WqkvT = (_Float16*)alloc((size_t)L * 3 * D * D * 2);
    float*     bqkv  = (float*)alloc((size_t)L * 3 * D * 4);
    _Float16*  WoT  = (_Float16*)alloc((size_t)L * D * D * 2);
    _Float16*  W1T  = (_Float16*)alloc((size_t)L * D * DFF * 2);
    _Float16*  W2T  = (_Float16*)alloc((size_t)L * DFF * D * 2);
    _Float16*  catT = (_Float16*)alloc((size_t)1024 * 256 * 2);   // padded to 1024 rows
    _Float16*  conT = (_Float16*)alloc((size_t)NCONT * 128 * 2);

    size_t need_ffh = (size_t)M * DFF * 2;
    _Float16* ffh;
    size_t offAl = (off + 255) & ~(size_t)255;
    if (offAl + need_ffh <= ws_size) ffh = (_Float16*)alloc(need_ffh);
    else ffh = (_Float16*)d_out;

    auto gemm = [&](const _Float16* A, long lda, long sA1, long sA2,
                    const _Float16* Bm, long ldb, long sB1, long sB2,
                    float* Cf, _Float16* Cb, long ldc, long sC1, long sC2,
                    const float* bias, long sb1, long sb2,
                    const _Float16* resid, int Mm, int Nn, int Kk,
                    int Z1, int Z2, float alpha, int relu, int deep) {
        dim3 gdim((Nn + 127) / 128, (Mm + 127) / 128, Z1 * Z2);
        if (deep)
            gemm_nt<1><<<gdim, 256, 0, stream>>>(A, lda, sA1, sA2, Bm, ldb, sB1, sB2,
                                                 Cf, Cb, ldc, sC1, sC2, bias, sb1, sb2,
                                                 resid, Mm, Nn, Kk, Z2, alpha, relu);
        else
            gemm_nt<0><<<gdim, 256, 0, stream>>>(A, lda, sA1, sA2, Bm, ldb, sB1, sB2,
                                                 Cf, Cb, ldc, sC1, sC2, bias, sb1, sb2,
                                                 resid, Mm, Nn, Kk, Z2, alpha, relu);
    };

    dim3 tb8(32, 8);
    // QKV weights concat -> [L][1536][512] NT form
    tcast_k<<<dim3(D / 32, D / 32, L), tb8, 0, stream>>>(Wq, WqkvT, D, D, (long)3 * D * D, 0);
    tcast_k<<<dim3(D / 32, D / 32, L), tb8, 0, stream>>>(Wk, WqkvT, D, D, (long)3 * D * D, D);
    tcast_k<<<dim3(D / 32, D / 32, L), tb8, 0, stream>>>(Wv, WqkvT, D, D, (long)3 * D * D, 2 * D);
    bcat_k<<<dim3((L * 1536 + 255) / 256), 256, 0, stream>>>(bq, bk, bv, bqkv, L);
    tcast_k<<<dim3(D / 32, D / 32, L), tb8, 0, stream>>>(Wo, WoT, D, D, (long)D * D, 0);
    tcast_k<<<dim3(DFF / 32, D / 32, L), tb8, 0, stream>>>(W1, W1T, D, DFF, (long)D * DFF, 0);
    tcast_k<<<dim3(D / 32, DFF / 32, L), tb8, 0, stream>>>(W2, W2T, DFF, D, (long)DFF * D, 0);
    cast_f32_f16_k<<<dim3(512), 256, 0, stream>>>(cat_table, catT, (long)NCAT * 256, (long)1024 * 256);
    cast_f32_f16_k<<<dim3(512), 256, 0, stream>>>(cont_tab, conT, (long)NCONT * 128, (long)NCONT * 128);

    embed_k<<<dim3((unsigned)M), 128, 0, stream>>>(ccat, ctime, cf0, tcat, ttime, tf0,
                                                   cat_table, pad_emb, xb, biasKey);

    for (int l = 0; l < L; l++) {
        // fused QKV projection: [M][1536] (grid-rich: BK=32)
        gemm(xb, D, 0, 0, WqkvT + (size_t)l * 3 * D * D, D, 0, 0, nullptr, qkv, 3 * D, 0, 0,
             bqkv + (size_t)l * 3 * D, 0, 0, nullptr, (int)M, 3 * D, D, 1, 1, 1.f, 0, 0);
        vtrans_k<<<dim3(32, 2, Bn * H), tb8, 0, stream>>>(qkv, vT);

        flash_k<<<dim3(Bn * H, S / 128), 512, 0, stream>>>(qkv, vT, biasKey, ob);

        // Wo: N=512 -> grid-starved -> BK=64; tb = ob@Wo + bo + xb
        gemm(ob, D, 0, 0, WoT + (size_t)l * D * D, D, 0, 0, nullptr, tb, D, 0, 0,
             bo + l * D, 0, 0, xb, (int)M, D, D, 1, 1, 1.f, 0, 1);
        layernorm_k<<<dim3((unsigned)(M / 4)), 256, 0, stream>>>(tb, hb, ln1g + l * D, ln1b + l * D);

        // W1: grid-rich -> BK=32
        gemm(hb, D, 0, 0, W1T + (size_t)l * D * DFF, D, 0, 0, nullptr, ffh, DFF, 0, 0,
             b1 + l * DFF, 0, 0, nullptr, (int)M, DFF, D, 1, 1, 1.f, 1, 0);
        // W2: N=512, K=2048 -> grid-starved long-K -> BK=64; tb = ffh@W2 + b2 + hb
        gemm(ffh, DFF, 0, 0, W2T + (size_t)l * DFF * D, DFF, 0, 0, nullptr, tb, D, 0, 0,
             b2 + l * D, 0, 0, hb, (int)M, D, DFF, 1, 1, 1.f, 0, 1);
        layernorm_k<<<dim3((unsigned)(M / 4)), 256, 0, stream>>>(tb, xb, ln2g + l * D, ln2b + l * D);
    }

    float* out_cat  = (float*)d_out;
    float* out_time = out_cat + (size_t)Bn * 512 * NCAT;
    float* out_f0   = out_time + (size_t)Bn * 512 * NCONT;
    gemm(xb + (size_t)512 * D, D, (long)S * D, 0,
         catT, 256, 0, 0,
         out_cat, nullptr, NCAT, (long)512 * NCAT, 0,
         nullptr, 0, 0, nullptr, 512, NCAT, 256, Bn, 1, 1.f, 0, 0);
    // fused time/f0 projection: Z1=16 batches, Z2=2 streams (A offset +128 cols,
    // C offset one full output block)
    gemm(xb + (size_t)512 * D + 256, D, (long)S * D, 128,
         conT, 128, 0, 0,
         out_time, nullptr, NCONT, (long)512 * NCONT, (long)Bn * 512 * NCONT,
         nullptr, 0, 0, nullptr, 512, NCONT, 128, Bn, 2, 1.f, 0, 0);
}